// Round 16
// baseline (181.308 us; speedup 1.0000x reference)
//
#include <hip/hip_runtime.h>
#include <hip/hip_bf16.h>
#include <cmath>

// ---------------------------------------------------------------------------
// NeuralField: hashgrid encode (8 levels x 8 feats, smoothstep) + MLP
// 64 -> 256 -> 256 -> 256 -> 1 (ReLU x3, linear out), N = 262144 points.
// R16: transpose the wave tile to 64 feats x 32 pts (fgrp = w&3 owns feats
// [64*fgrp,+64), pgrp = w>>2 owns pts [32*pgrp,+32)). Per kb: 2 wf (L2) +
// ONE af ds_read_b128 + 2 MFMA -> K-loop LDS reads halve (R15 analysis:
// LDS pipe ~46 us/CU was the top un-modeled resource; af reads dominate).
// Weight L2 traffic doubles (1.18->2.36 GB) -- proven non-binding in R15.
// Epilogue pack via __float22bfloat162_rn (v_cvt_pk_bf16_f32, RNE,
// bit-identical to manual f2bf). Rest = R12/R13: TILE_M=64, bufE encode
// staging, L1 in-place w/ internal barrier, L2+final fused, (512,6),
// 43 KB LDS -> 3 blocks/CU. Spill tripwire: FETCH/WRITE >> 5 MB.
// ---------------------------------------------------------------------------

#define N_LEVELS 8
#define TABLE_PAD 8192
#define TILE_M 64
#define ACT_STRIDE 264       // shorts per activation row
#define ENC_STRIDE 72        // shorts per encode row

typedef __attribute__((ext_vector_type(8))) short short8;
typedef __attribute__((ext_vector_type(16))) float float16v;

struct LevelParams {
  float scale[N_LEVELS];
  int   res[N_LEVELS];
  int   size[N_LEVELS];
};

__device__ __forceinline__ unsigned short f2bf(float f) {
  unsigned int u = __float_as_uint(f);
  u += 0x7fffu + ((u >> 16) & 1u);      // round to nearest even
  return (unsigned short)(u >> 16);
}
__device__ __forceinline__ unsigned int pack2bf_relu(float a, float b) {
  a = a > 0.f ? a : 0.f;
  b = b > 0.f ? b : 0.f;
  __hip_bfloat162 h = __float22bfloat162_rn(make_float2(a, b));
  return *(unsigned int*)&h;            // v_cvt_pk_bf16_f32 (RNE)
}

// Pack W (K x 256 row-major f32) -> bf16 [k/16][n][k%16]: one lane's 16 B
// A-frag for 32x32x16 (feature n, k-half h8) is contiguous at n*16 + h8*8.
// Wp layout: [W0p: 4*4096][W1p: 16*4096][W2p: 16*4096] shorts.
__global__ void pack_weights_kernel(const float* __restrict__ W0,
                                    const float* __restrict__ W1,
                                    const float* __restrict__ W2,
                                    unsigned short* __restrict__ Wp) {
  int tid = blockIdx.x * blockDim.x + threadIdx.x;
  const float* src;
  int base, e;
  if (tid < 16384)        { src = W0; base = 0;     e = tid;         }
  else if (tid < 81920)   { src = W1; base = 16384; e = tid - 16384; }
  else if (tid < 147456)  { src = W2; base = 81920; e = tid - 81920; }
  else return;
  int ki = e & 15;
  int n  = (e >> 4) & 255;
  int kb = e >> 12;
  unsigned int u = __float_as_uint(src[(kb * 16 + ki) * 256 + n]);
  u += 0x7fffu + ((u >> 16) & 1u);
  Wp[base + e] = (unsigned short)(u >> 16);
}

__global__ __launch_bounds__(512, 6) void neural_field_kernel(
    const float* __restrict__ x,
    const float* __restrict__ table,
    const unsigned short* __restrict__ Wp,
    const float* __restrict__ W3,
    float* __restrict__ out,
    LevelParams P) {
  // Padded layouts, data stored [point m][feature k]:
  //   enc: (m, k) -> m*72 + k      act: (m, k) -> m*264 + k
  __shared__ unsigned short bufE[TILE_M * ENC_STRIDE];   //  9 KB (-> fsum)
  __shared__ unsigned short bufA[TILE_M * ACT_STRIDE];   // 33 KB, in-place

  const int t  = threadIdx.x;
  const int g0 = blockIdx.x * TILE_M;

  const int lane  = t & 63;
  const int w     = t >> 6;       // 0..7
  const int l31   = lane & 31;
  const int h8    = lane >> 5;    // 0/1: k-half within a 16-k step
  const int fgrp  = w & 3;        // feature group: feats [fgrp*64, +64)
  const int pgrp  = w >> 2;       // point group:   pts   [pgrp*32, +32)
  const int fbase = fgrp * 64;
  const int mrow  = pgrp * 32 + l31;   // this lane's point (B-frag col)

  // Weight A-frag base offset (elements) for feature sub-group f2=0;
  // f2=1 is +512 (32 feats * 16).
  const int woff = (fbase + l31) * 16 + h8 * 8;

  // ------------- Phase 1: hashgrid encode, 1 level/thread -> bufE ----------
  {
    int p = t & 63;        // point within tile
    int l = t >> 6;        // level 0..7
    float2 xy = ((const float2*)x)[g0 + p];
    float scale = P.scale[l];
    int res = P.res[l], size = P.size[l];
    float posx = xy.x * scale + 0.5f;
    float posy = xy.y * scale + 0.5f;
    float pgx = floorf(posx), pgy = floorf(posy);
    float fx = posx - pgx, fy = posy - pgy;
    float wx = fx * fx * (3.0f - 2.0f * fx);
    float wy = fy * fy * (3.0f - 2.0f * fy);
    int px = (int)pgx, py = (int)pgy;
    float acc[8] = {0, 0, 0, 0, 0, 0, 0, 0};
    for (int dy = 0; dy < 2; ++dy) {
      float wyv = dy ? wy : 1.0f - wy;
      for (int dx = 0; dx < 2; ++dx) {
        float wgt = (dx ? wx : 1.0f - wx) * wyv;
        int idx = (px + dx) + (py + dy) * res;
        if (idx >= size) idx -= size;   // idx < 2*size always
        const float4* tp =
            (const float4*)(table + ((size_t)l * TABLE_PAD + idx) * 8);
        float4 t0 = tp[0], t1 = tp[1];
        acc[0] += wgt * t0.x; acc[1] += wgt * t0.y;
        acc[2] += wgt * t0.z; acc[3] += wgt * t0.w;
        acc[4] += wgt * t1.x; acc[5] += wgt * t1.y;
        acc[6] += wgt * t1.z; acc[7] += wgt * t1.w;
      }
    }
    union { unsigned short s[8]; short8 v; } u;
    for (int j = 0; j < 8; ++j) u.s[j] = f2bf(acc[j]);
    *(short8*)&bufE[p * ENC_STRIDE + l * 8] = u.v;
  }

  // --- MFMA layer (transposed, 32x32x16): D = W^T[64 x K] @ X^T[K x 32] ----
  // A-frag (weights): row n = fbase + f2*32 + l31, k = kb*16 + h8*8 + j.
  // B-frag (acts):    col m = mrow,                k = kb*16 + h8*8 + j.
  // D tile f2: col m = mrow; rows reg 4q+r -> n = fbase + f2*32 + 8q+4h8+r.
  auto run_layer = [&](const unsigned short* inb, int in_stride,
                       const unsigned short* Wpl, int KB,
                       bool inplace, bool fuse_final, float* fsum) {
    float16v acc[2];
    for (int j = 0; j < 16; ++j) { acc[0][j] = 0.f; acc[1][j] = 0.f; }

    const unsigned short* ap = &inb[mrow * in_stride + h8 * 8];
    const unsigned short* wp = Wpl + woff;

#pragma unroll
    for (int kb = 0; kb < KB; ++kb) {
      short8 wf0 = *(const short8*)(wp + kb * 4096);
      short8 wf1 = *(const short8*)(wp + kb * 4096 + 512);
      short8 af  = *(const short8*)(ap + kb * 16);
      acc[0] = __builtin_amdgcn_mfma_f32_32x32x16_bf16(wf0, af, acc[0],
                                                       0, 0, 0);
      acc[1] = __builtin_amdgcn_mfma_f32_32x32x16_bf16(wf1, af, acc[1],
                                                       0, 0, 0);
    }

    if (inplace) __syncthreads();   // all K-loop reads done before overwrite

    if (!fuse_final) {
      // Epilogue: ReLU + packed bf16 cvt; 8 b64 writes, already in the next
      // layer's [m][k-contiguous] layout.
      for (int f2 = 0; f2 < 2; ++f2) {
        for (int q = 0; q < 4; ++q) {
          int n0 = fbase + f2 * 32 + 8 * q + 4 * h8;
          uint2 pk;
          pk.x = pack2bf_relu(acc[f2][4 * q + 0], acc[f2][4 * q + 1]);
          pk.y = pack2bf_relu(acc[f2][4 * q + 2], acc[f2][4 * q + 3]);
          *(uint2*)&bufA[mrow * ACT_STRIDE + n0] = pk;
        }
      }
    } else {
      // Fused final layer: per-lane relu-dot over this wave's 64 features
      // (32 per k-half across f2); shfl_xor(32) completes the 64-feat sum
      // for col m = mrow; h8==0 lane stages fsum[m*5 + fgrp].
      float s = 0.f;
      for (int f2 = 0; f2 < 2; ++f2) {
        for (int q = 0; q < 4; ++q) {
          float4 wv = *(const float4*)(W3 + fbase + f2 * 32 + 8 * q + 4 * h8);
          float v0 = acc[f2][4 * q + 0]; v0 = v0 > 0.f ? v0 : 0.f;
          float v1 = acc[f2][4 * q + 1]; v1 = v1 > 0.f ? v1 : 0.f;
          float v2 = acc[f2][4 * q + 2]; v2 = v2 > 0.f ? v2 : 0.f;
          float v3 = acc[f2][4 * q + 3]; v3 = v3 > 0.f ? v3 : 0.f;
          s += v0 * wv.x + v1 * wv.y + v2 * wv.z + v3 * wv.w;
        }
      }
      s += __shfl_xor(s, 32);
      if (h8 == 0) fsum[mrow * 5 + fgrp] = s;
    }
  };

  float* fsum = (float*)bufE;           // bufE dead after layer 0

  __syncthreads();
  // Layer 0: bufE -> bufA (disjoint, no in-place hazard)
  run_layer(bufE, ENC_STRIDE, Wp,         4,  false, false, fsum);
  __syncthreads();
  // Layer 1: bufA -> bufA IN-PLACE (mid-layer barrier inside)
  run_layer(bufA, ACT_STRIDE, Wp + 16384, 16, true,  false, fsum);
  __syncthreads();
  // Layer 2 + final: reads bufA, writes only fsum (bufE region, disjoint)
  run_layer(bufA, ACT_STRIDE, Wp + 81920, 16, false, true,  fsum);
  __syncthreads();

  // ---------------- Cross-wave reduce of fsum -> out -----------------------
  if (t < 256) {
    int p = t >> 2;          // point within tile (0..63)
    int q = t & 3;           // feature group being summed
    float v = fsum[p * 5 + q];
    v += __shfl_xor(v, 1);
    v += __shfl_xor(v, 2);
    if (q == 0) out[g0 + p] = v;
  }
}

extern "C" void kernel_launch(void* const* d_in, const int* in_sizes, int n_in,
                              void* d_out, int out_size, void* d_ws,
                              size_t ws_size, hipStream_t stream) {
  const float* x     = (const float*)d_in[0];
  const float* table = (const float*)d_in[1];
  const float* W0    = (const float*)d_in[2];
  const float* W1    = (const float*)d_in[3];
  const float* W2    = (const float*)d_in[4];
  const float* W3    = (const float*)d_in[5];
  float* out = (float*)d_out;
  int N = in_sizes[0] / 2;

  unsigned short* Wp = (unsigned short*)d_ws;   // 147456 bf16 = 288 KB

  // Level params, double precision to match the Python reference exactly.
  LevelParams P;
  const double c = 1.2599210739135742;
  double m = 1.0;
  for (int l = 0; l < N_LEVELS; ++l) {
    double scale_d = 16.0 * m - 1.0;
    int res = (int)std::ceil(scale_d) + 1;
    long long sz = ((long long)res * res + 7) / 8 * 8;
    if (sz > (1LL << 19)) sz = 1LL << 19;
    P.scale[l] = (float)scale_d;
    P.res[l]   = res;
    P.size[l]  = (int)sz;
    m *= c;
  }

  hipLaunchKernelGGL(pack_weights_kernel, dim3(576), dim3(256), 0, stream,
                     W0, W1, W2, Wp);
  hipLaunchKernelGGL(neural_field_kernel, dim3(N / TILE_M), dim3(512), 0,
                     stream, x, table, Wp, W3, out, P);
}